// Round 11
// baseline (246.385 us; speedup 1.0000x reference)
//
#include <hip/hip_runtime.h>

// Problem constants
#define BB   2
#define SS   4096
#define DD   1024
#define HH   16
#define DHH  64
#define WW   256
#define GG   64
#define NBLK 16    // S/W

typedef unsigned short ushort_t;
typedef unsigned long long u64;
typedef short  s16x8 __attribute__((ext_vector_type(8)));
typedef float  f32x4 __attribute__((ext_vector_type(4)));

// 0.125 * log2(e): folded into q at QKV-GEMM epilogue time.
#define QSCALE 0.18033688011112042f

#define VMCNT(n) asm volatile("s_waitcnt vmcnt(" #n ")" ::: "memory")

// fp32 -> bf16 round-to-nearest-even, raw bits
__device__ __forceinline__ ushort_t f2b(float f) {
  unsigned int u = __builtin_bit_cast(unsigned int, f);
  unsigned int r = (u + 0x7fffu + ((u >> 16) & 1u)) >> 16;
  return (ushort_t)r;
}

// single-op fp32 -> bf16 (RNE) via v_cvt_pk_bf16_f32, low half used
__device__ __forceinline__ ushort_t f2b1(float f) {
  unsigned int r;
  asm("v_cvt_pk_bf16_f32 %0, %1, %2" : "=v"(r) : "v"(f), "v"(f));
  return (ushort_t)r;
}

// pack two fp32 -> one u32 of 2 bf16 (low = a, high = b)
__device__ __forceinline__ unsigned int pk2(float a, float b) {
  unsigned int r;
  asm("v_cvt_pk_bf16_f32 %0, %1, %2" : "=v"(r) : "v"(a), "v"(b));
  return r;
}

__device__ __forceinline__ float exp2f_fast(float x) {
  return __builtin_amdgcn_exp2f(x);
}

// Async 16B global->LDS DMA. LDS dst must be wave-uniform base + lane*16.
__device__ __forceinline__ void gld16(const void* g, void* l) {
  __builtin_amdgcn_global_load_lds(
      (const __attribute__((address_space(1))) void*)g,
      (__attribute__((address_space(3))) void*)l, 16, 0, 0);
}

// ---------------------------------------------------------------------------
// x (fp32) -> bf16, flat. 4096 blocks x 256 thr x 8 elems.
// ---------------------------------------------------------------------------
__global__ __launch_bounds__(256) void xcast(
    const float* __restrict__ x, ushort_t* __restrict__ xb) {
  size_t i = ((size_t)blockIdx.x * 256 + threadIdx.x) * 8;
  float4 f0 = *(const float4*)&x[i];
  float4 f1 = *(const float4*)&x[i + 4];
  ushort_t t[8];
  t[0] = f2b(f0.x); t[1] = f2b(f0.y); t[2] = f2b(f0.z); t[3] = f2b(f0.w);
  t[4] = f2b(f1.x); t[5] = f2b(f1.y); t[6] = f2b(f1.z); t[7] = f2b(f1.w);
  *(uint4*)&xb[i] = *(const uint4*)t;
}

// ---------------------------------------------------------------------------
// Transpose + fp32->bf16 the four weight matrices into (n,k) bf16 layout.
// ---------------------------------------------------------------------------
__global__ __launch_bounds__(256) void transpose_w(
    const float* __restrict__ Wq, const float* __restrict__ Wk,
    const float* __restrict__ Wv, const float* __restrict__ Wo,
    ushort_t* __restrict__ outBase) {
  const float* src = (blockIdx.z == 0) ? Wq : (blockIdx.z == 1) ? Wk
                    : (blockIdx.z == 2) ? Wv : Wo;
  ushort_t* dst = outBase + (size_t)blockIdx.z * (1024 * 1024);
  __shared__ __align__(16) ushort_t t[64][72];
  const int tid = threadIdx.x;
  const int bx = blockIdx.x * 64, by = blockIdx.y * 64;
  const int c4 = (tid & 15) * 4;
  const int r16 = tid >> 4;
  for (int rr = r16; rr < 64; rr += 16) {
    float4 f = *(const float4*)&src[(size_t)(by + rr) * 1024 + bx + c4];
    t[c4 + 0][rr] = f2b(f.x);
    t[c4 + 1][rr] = f2b(f.y);
    t[c4 + 2][rr] = f2b(f.z);
    t[c4 + 3][rr] = f2b(f.w);
  }
  __syncthreads();
  const int sr = tid >> 3;
  const int sc = (tid & 7) * 8;
  for (int rr = sr; rr < 64; rr += 32) {
    *(uint4*)&dst[(size_t)(bx + rr) * 1024 + by + sc] = *(const uint4*)&t[rr][sc];
  }
}

// ---------------------------------------------------------------------------
// QKV GEMM: 256x256 tile, 8-phase pipelined schedule — EXACT round-4/6 kernel
// (best measured: ~75 us). 2-D super-tile XCD swizzle + v-block LDS-transpose
// epilogue. See round-4 comments for the vmcnt/slab ledger.
// ---------------------------------------------------------------------------
__global__ __launch_bounds__(512, 2) void gemm256(
    const ushort_t* __restrict__ A, const ushort_t* __restrict__ Bt,
    ushort_t* __restrict__ O0, ushort_t* __restrict__ O1,
    ushort_t* __restrict__ O2, float* __restrict__ Of, int K) {
  __shared__ __align__(16) ushort_t SH[65536];

  const int tid  = threadIdx.x;        // 0..511
  const int lane = tid & 63;
  const int w    = tid >> 6;           // 0..7
  const int quad = lane >> 4;          // 0..3
  const int l16  = lane & 15;
  const int wr   = w >> 2;             // 0..1  (M)
  const int wc   = w & 3;              // 0..3  (N)

  // 2-D super-tile XCD swizzle (gridDim.x must be 32)
  const int id  = blockIdx.x + (gridDim.x * blockIdx.y);
  const int xcd = id & 7;
  const int seq = id >> 3;
  const int nx  = (xcd << 2) + (seq & 3);
  const int ny  = seq >> 2;
  const int bm  = nx * 256;
  const int bn  = ny * 256;

  auto Aslab = [&](int buf, int kkh) -> ushort_t* {
    return &SH[(buf * 2 + kkh) * 8192];
  };
  auto Bslab = [&](int buf, int kkh) -> ushort_t* {
    return &SH[32768 + (buf * 2 + kkh) * 8192];
  };

  const int srow = tid >> 2;                        // 0..127
  const int sch  = (tid & 3) ^ ((srow >> 1) & 3);   // source 16B chunk in row
  const ushort_t* Ag = A + (size_t)(bm + srow) * K + sch * 8;
  const ushort_t* Bg = Bt + (size_t)(bn + srow) * K + sch * 8;

  const int chofs = ((quad ^ ((l16 >> 1) & 3)) << 3);

  auto stage = [&](ushort_t* slab, const ushort_t* g) {
    gld16(g, &slab[tid * 8]);
    gld16(g + (size_t)128 * K, &slab[4096 + tid * 8]);
  };

  f32x4 acc[8][4] = {};
  s16x8 afrag[4], bfrag[4];

  auto ldA = [&](int buf, int kkh, int i) {
    const int row = wr * 128 + i * 16 + l16;
    return *(const s16x8*)&Aslab(buf, kkh)[row * 32 + chofs];
  };
  auto ldB = [&](int buf, int kkh, int j) {
    const int row = wc * 64 + j * 16 + l16;
    return *(const s16x8*)&Bslab(buf, kkh)[row * 32 + chofs];
  };
  auto mfma16 = [&](int ih) {
    __builtin_amdgcn_s_setprio(1);
#pragma unroll
    for (int t = 0; t < 4; t++)
#pragma unroll
      for (int j = 0; j < 4; j++)
        acc[ih * 4 + t][j] = __builtin_amdgcn_mfma_f32_16x16x32_bf16(
            afrag[t], bfrag[j], acc[ih * 4 + t][j], 0, 0, 0);
    __builtin_amdgcn_s_setprio(0);
  };

  const int NT = K >> 6;

  stage(Bslab(0, 0), Bg);
  stage(Aslab(0, 0), Ag);
  stage(Bslab(0, 1), Bg + 32);
  stage(Aslab(0, 1), Ag + 32);
  VMCNT(4);
  stage(Bslab(1, 0), Bg + 64);
  stage(Aslab(1, 0), Ag + 64);
  stage(Bslab(1, 1), Bg + 96);
  VMCNT(6);
  __builtin_amdgcn_s_barrier();

#pragma unroll 1
  for (int kt = 0; kt < NT; ++kt) {
    const int buf = kt & 1;
    // phase 1: kk0, m 0..3
#pragma unroll
    for (int j = 0; j < 4; j++) bfrag[j] = ldB(buf, 0, j);
#pragma unroll
    for (int t = 0; t < 4; t++) afrag[t] = ldA(buf, 0, t);
    if (kt + 1 < NT) stage(Aslab(buf ^ 1, 1), Ag + (size_t)(kt + 1) * 64 + 32);
    __builtin_amdgcn_s_barrier();
    asm volatile("s_waitcnt lgkmcnt(0)" ::: "memory");
    mfma16(0);
    __builtin_amdgcn_s_barrier();
    // phase 2: kk0, m 4..7
#pragma unroll
    for (int t = 0; t < 4; t++) afrag[t] = ldA(buf, 0, 4 + t);
    if (kt + 2 < NT) stage(Bslab(buf, 0), Bg + (size_t)(kt + 2) * 64);
    __builtin_amdgcn_s_barrier();
    asm volatile("s_waitcnt lgkmcnt(0)" ::: "memory");
    mfma16(1);
    __builtin_amdgcn_s_barrier();
    // phase 3: kk1, m 0..3
#pragma unroll
    for (int j = 0; j < 4; j++) bfrag[j] = ldB(buf, 1, j);
#pragma unroll
    for (int t = 0; t < 4; t++) afrag[t] = ldA(buf, 1, t);
    if (kt + 2 < NT) stage(Aslab(buf, 0), Ag + (size_t)(kt + 2) * 64);
    __builtin_amdgcn_s_barrier();
    asm volatile("s_waitcnt lgkmcnt(0)" ::: "memory");
    mfma16(0);
    __builtin_amdgcn_s_barrier();
    // phase 4: kk1, m 4..7; counted vmcnt
#pragma unroll
    for (int t = 0; t < 4; t++) afrag[t] = ldA(buf, 1, 4 + t);
    if (kt + 2 < NT) {
      stage(Bslab(buf, 1), Bg + (size_t)(kt + 2) * 64 + 32);
      VMCNT(6);
    } else if (kt + 1 < NT) {
      VMCNT(0);
    }
    __builtin_amdgcn_s_barrier();
    asm volatile("s_waitcnt lgkmcnt(0)" ::: "memory");
    mfma16(1);
    __builtin_amdgcn_s_barrier();
  }

  // Epilogue. C/D layout: row = quad*4 + reg, col = lane&15.
  if (bn >= 2048) {
    // v-block: LDS transpose, coalesced 16B stores.
    const int bb = bm >> 12;
    const int n1b = bn & 1023;
    const int sb  = bm & 4095;
#pragma unroll 1
    for (int p = 0; p < 2; p++) {
      __syncthreads();
      if (wr == p) {
#pragma unroll
        for (int i = 0; i < 8; i++)
#pragma unroll
          for (int j = 0; j < 4; j++)
#pragma unroll
            for (int r = 0; r < 4; r++)
              SH[(wc * 64 + j * 16 + l16) * 136 + i * 16 + quad * 4 + r] =
                  f2b(acc[i][j][r]);
      }
      __syncthreads();
#pragma unroll
      for (int it = 0; it < 8; it++) {
        const int row = it * 32 + (tid >> 4);
        const int n1 = n1b + row;
        const int dh = n1 & 63, hh = n1 >> 6;
        const int s = sb + p * 128 + (tid & 15) * 8;
        uint4 val = *(const uint4*)&SH[row * 136 + (tid & 15) * 8];
        *(uint4*)&O2[(((size_t)bb * HH + hh) * DHH + dh) * SS + s] = val;
      }
    }
  } else {
#pragma unroll
    for (int i = 0; i < 8; i++) {
#pragma unroll
      for (int j = 0; j < 4; j++) {
#pragma unroll
        for (int r = 0; r < 4; r++) {
          int m = bm + wr * 128 + i * 16 + quad * 4 + r;
          int n = bn + wc * 64 + j * 16 + l16;
          float av = acc[i][j][r];
          int n1 = n & 1023;
          int h = n1 >> 6, dh = n1 & 63;
          int b = m >> 12, s = m & 4095;
          if (n < 1024) {
            O0[(((size_t)b * HH + h) * SS + s) * DHH + dh] = f2b(av * QSCALE);
          } else {
            O1[(((size_t)b * HH + h) * SS + s) * DHH + dh] = f2b(av);
          }
        }
      }
    }
  }
}

// ---------------------------------------------------------------------------
// Output-projection GEMM (unchanged from round 6): 128x128 tile, BK=32,
// double-buffered 32 KiB LDS, 4 blocks/CU, counted VMCNT(4), XCD swizzle.
// ---------------------------------------------------------------------------
__global__ __launch_bounds__(256, 4) void gemmk128(
    const ushort_t* __restrict__ A, const ushort_t* __restrict__ Bt,
    float* __restrict__ Of, int K) {
  __shared__ __align__(16) ushort_t As[2][128 * 32];
  __shared__ __align__(16) ushort_t Bs[2][128 * 32];

  const int tid  = threadIdx.x;        // 0..255
  const int lane = tid & 63;
  const int w    = tid >> 6;           // 0..3
  const int quad = lane >> 4;
  const int l16  = lane & 15;
  const int wr   = w >> 1;             // 0..1 (M)
  const int wc   = w & 1;              // 0..1 (N)

  // 2-D super-tile XCD swizzle (gridDim.x == 64)
  const int id  = blockIdx.x + (gridDim.x * blockIdx.y);
  const int xcd = id & 7;
  const int seq = id >> 3;
  const int nx  = (xcd << 3) + (seq & 7);
  const int ny  = seq >> 3;
  const int bm  = nx * 128;
  const int bn  = ny * 128;

  const int srow = tid >> 2;                        // 0..63
  const int sch  = (tid & 3) ^ ((srow >> 1) & 3);
  const ushort_t* Ag = A + (size_t)(bm + srow) * K + sch * 8;
  const ushort_t* Bg = Bt + (size_t)(bn + srow) * K + sch * 8;
  const int sch2 = (tid & 3) ^ (((srow + 64) >> 1) & 3);
  const ushort_t* Ag2 = A + (size_t)(bm + srow + 64) * K + sch2 * 8;
  const ushort_t* Bg2 = Bt + (size_t)(bn + srow + 64) * K + sch2 * 8;

  const int chofs = ((quad ^ ((l16 >> 1) & 3)) << 3);

  auto stage = [&](int buf, int s) {
    gld16(Ag + (size_t)s * 32, &As[buf][tid * 8]);
    gld16(Ag2 + (size_t)s * 32, &As[buf][2048 + tid * 8]);
    gld16(Bg + (size_t)s * 32, &Bs[buf][tid * 8]);
    gld16(Bg2 + (size_t)s * 32, &Bs[buf][2048 + tid * 8]);
  };

  f32x4 acc[4][4] = {};

  const int NT = K >> 5;   // 32 K-steps

  stage(0, 0);
  VMCNT(0);
  __builtin_amdgcn_s_barrier();

#pragma unroll 1
  for (int s = 0; s < NT; ++s) {
    const int buf = s & 1;
    if (s + 1 < NT) {
      stage(buf ^ 1, s + 1);
      VMCNT(4);                      // stage(s) landed; stage(s+1) in flight
    } else {
      VMCNT(0);
    }
    __builtin_amdgcn_s_barrier();
    s16x8 afrag[4], bfrag[4];
#pragma unroll
    for (int t = 0; t < 4; t++)
      afrag[t] = *(const s16x8*)&As[buf][(wr * 64 + t * 16 + l16) * 32 + chofs];
#pragma unroll
    for (int j = 0; j < 4; j++)
      bfrag[j] = *(const s16x8*)&Bs[buf][(wc * 64 + j * 16 + l16) * 32 + chofs];
    asm volatile("s_waitcnt lgkmcnt(0)" ::: "memory");
    __builtin_amdgcn_s_setprio(1);
#pragma unroll
    for (int t = 0; t < 4; t++)
#pragma unroll
      for (int j = 0; j < 4; j++)
        acc[t][j] = __builtin_amdgcn_mfma_f32_16x16x32_bf16(
            afrag[t], bfrag[j], acc[t][j], 0, 0, 0);
    __builtin_amdgcn_s_setprio(0);
    __builtin_amdgcn_s_barrier();
  }

  // Epilogue: fp32 row-major. C/D: row = quad*4 + r, col = l16.
#pragma unroll
  for (int i = 0; i < 4; i++) {
#pragma unroll
    for (int j = 0; j < 4; j++) {
#pragma unroll
      for (int r = 0; r < 4; r++) {
        int m = bm + wr * 64 + i * 16 + quad * 4 + r;
        int n = bn + wc * 64 + j * 16 + l16;
        Of[(size_t)m * DD + n] = acc[i][j][r];
      }
    }
  }
}

// ---------------------------------------------------------------------------
// Attention v6 (RETRY — round-10 bench was the session's third opaque
// container failure; audit found no hang/fault source: barriers uniform
// per-iteration, vmcnt ledger satisfiable, WAR ordered by barrier+lgkm,
// all addresses in-bounds, LDS 80KB = 2 blocks/CU. Identical resubmit per
// round-2 precedent. Pre-committed: any failure next round -> revert to v5.)
//   Block-shared pipelined K/V staging (counted vmcnt, no drain) on v5's
//   verified swapped-QK P-path. 3-deep rotating K/V LDS buffers; per iter:
//   {VMCNT(4) -> s_barrier -> issue stage(i+2) -> compute(i)}; never
//   vmcnt(0) mid-loop. K/V traffic /3 vs per-wave loads; V gets ~2-chunk
//   prefetch distance.
// ---------------------------------------------------------------------------
__global__ __launch_bounds__(256, 2) void attn_kernel(
    const ushort_t* __restrict__ q, const ushort_t* __restrict__ k,
    const ushort_t* __restrict__ vT, ushort_t* __restrict__ out) {
  const int blk = blockIdx.x;
  const int h   = blockIdx.y;
  const int b   = blockIdx.z;
  const int tid  = threadIdx.x;
  const int lane = tid & 63;
  const int w    = tid >> 6;
  const int quad = lane >> 4;
  const int l16  = lane & 15;
  const int l7   = l16 & 7;

  const size_t bh = ((size_t)b * HH + h) * SS * DHH;
  const ushort_t* qb  = q + bh;
  const ushort_t* kb  = k + bh;
  const ushort_t* vtb = vT + bh;   // layout [dh][s], row stride SS

  __shared__ __align__(16) ushort_t Ks[3][64 * 64];   // 24 KB
  __shared__ __align__(16) ushort_t Vs[3][64 * 64];   // 24 KB
  __shared__ __align__(16) ushort_t Ps[4][64 * 64];   // 32 KB, per-wave P
  ushort_t* Pw = &Ps[w][0];

  const int q0 = blk * WW + w * 64;

  // P elem offsets (v5 layout): elem(q,k) = q*64 + (((k>>3)^(q&7))<<3)+(k&7)
  const int wofs = l16 * 64 + 4 * (quad & 1);     // + mt*1024 + chunk'(nt)*8
  const int hq1  = quad >> 1;
  const int rofs = l16 * 64;                      // + mt*1024 + chunkR*8

  // --- block-uniform compact chunk list ---
  int list[13];
  int n = 0;
#pragma unroll
  for (int c = 0; c < 12; c++) {
    int j = blk * WW - WW + c * 64;
    if (j >= GG && j < SS) list[n++] = j;
  }
  list[n++] = 0;                                  // global chunk last

  // --- staging: 4 x gld16/thread per chunk (K 2 passes + V 2 passes) ---
  const int srow = tid >> 3;                      // 0..31
  const int schw = (tid & 7) ^ (srow & 7);        // source col-chunk (swz)
  auto stageKV = [&](int buf, int j0s) {
    const ushort_t* kc = kb + (size_t)(j0s + srow) * DHH + schw * 8;
    const ushort_t* vc = vtb + (size_t)srow * SS + j0s + schw * 8;
    gld16(kc,                    &Ks[buf][tid * 8]);
    gld16(kc + (size_t)32 * DHH, &Ks[buf][2048 + tid * 8]);
    gld16(vc,                    &Vs[buf][tid * 8]);
    gld16(vc + (size_t)32 * SS,  &Vs[buf][2048 + tid * 8]);
  };
  // fragment reads: row = t*16 + l16, col-chunk (x*4+quad) ^ (l16&7)
  auto ldK = [&](int buf, int nt, int x) {
    return *(const s16x8*)&Ks[buf][(nt * 16 + l16) * 64 + (((x << 2) + quad) ^ l7) * 8];
  };
  auto ldV = [&](int buf, int dt, int x) {
    return *(const s16x8*)&Vs[buf][(dt * 16 + l16) * 64 + (((x << 2) + quad) ^ l7) * 8];
  };

  // --- Q fragments (per-wave, registers) ---
  s16x8 aq[4][2];
#pragma unroll
  for (int mt = 0; mt < 4; mt++)
#pragma unroll
    for (int x = 0; x < 2; x++)
      aq[mt][x] = *(const s16x8*)&qb[(size_t)(q0 + mt * 16 + l16) * DHH + x * 32 + quad * 8];

  f32x4 oacc[4][4] = {};
  f32x4 rsacc[4] = {};

  s16x8 vone;
#pragma unroll
  for (int j = 0; j < 8; j++) vone[j] = (short)0x3F80;   // bf16 1.0

  // --- prologue: stage chunks 0,1 (n >= 8 always) ---
  stageKV(0, list[0]);
  stageKV(1, list[1]);

#pragma unroll 1
  for (int i = 0; i < n; i++) {
    if (i + 1 < n) { VMCNT(4); } else { VMCNT(0); }
    __builtin_amdgcn_s_barrier();
    if (i + 2 < n) stageKV((i + 2) % 3, list[i + 2]);

    const int buf = i - (i / 3) * 3;             // i % 3
    const int j0 = list[i];
    const bool isglb = (i == n - 1);
    const int dlt = j0 - q0;
    const bool haswork = isglb || (dlt >= -319 && dlt <= 319);
    if (!haswork) continue;
    const bool needmask = !isglb && (dlt < -193 || dlt > 193);

    // --- QK^T (swapped: S^T) + exp2 + packed b64 P-writes ---
#pragma unroll
    for (int nt = 0; nt < 4; nt++) {
      s16x8 bk0 = ldK(buf, nt, 0);
      s16x8 bk1 = ldK(buf, nt, 1);
      const int jbase = j0 + nt * 16 + quad * 4;   // k index of reg r=0
#pragma unroll
      for (int mt = 0; mt < 4; mt++) {
        f32x4 s4 = {0.f, 0.f, 0.f, 0.f};
        s4 = __builtin_amdgcn_mfma_f32_16x16x32_bf16(bk0, aq[mt][0], s4, 0, 0, 0);
        s4 = __builtin_amdgcn_mfma_f32_16x16x32_bf16(bk1, aq[mt][1], s4, 0, 0, 0);
        float p[4];
#pragma unroll
        for (int r = 0; r < 4; r++) {
          if (needmask) {
            int d = jbase + r - (q0 + mt * 16 + l16);
            p[r] = (d <= (int)WW && d >= -(int)WW) ? exp2f_fast(s4[r]) : 0.0f;
          } else {
            p[r] = exp2f_fast(s4[r]);
          }
        }
        unsigned int lo = pk2(p[0], p[1]);
        unsigned int hi = pk2(p[2], p[3]);
        u64 val = __builtin_bit_cast(u64, (uint2){lo, hi});
        const int ch = ((nt << 1) | hq1) ^ l7;       // swizzled 8-elem chunk
        *(u64*)&Pw[wofs + mt * 1024 + ch * 8] = val;
      }
    }

    // --- PV + ones-MFMA row sums (P via swizzled b128, V from LDS) ---
    __builtin_amdgcn_s_setprio(1);
#pragma unroll
    for (int ll = 0; ll < 64; ll += 32) {
      s16x8 ap[4], bv_[4];
#pragma unroll
      for (int mt = 0; mt < 4; mt++) {
        const int chR = (quad + (ll >> 3)) ^ l7;
        ap[mt] = *(const s16x8*)&Pw[rofs + mt * 1024 + chR * 8];
      }
#pragma unroll
      for (int dt = 0; dt < 4; dt++) bv_[dt] = ldV(buf, dt, ll >> 5);
#pragma unroll
      for (int mt = 0; mt < 4; mt++) {
        rsacc[mt] = __builtin_amdgcn_mfma_f32_16x16x32_bf16(ap[mt], vone, rsacc[mt], 0, 0, 0);
#pragma unroll
        for (int dt = 0; dt < 4; dt++)
          oacc[mt][dt] = __builtin_amdgcn_mfma_f32_16x16x32_bf16(ap[mt], bv_[dt], oacc[mt][dt], 0, 0, 0);
      }
    }
    __builtin_amdgcn_s_setprio(0);
  }

#pragma unroll
  for (int mt = 0; mt < 4; mt++) {
#pragma unroll
    for (int r = 0; r < 4; r++) {
      float inv = __builtin_amdgcn_rcpf(rsacc[mt][r]);
      int srow2 = q0 + mt * 16 + quad * 4 + r;
      size_t orow = ((size_t)b * SS + srow2) * DD + h * DHH;
#pragma unroll
      for (int dt = 0; dt < 4; dt++)
        out[orow + dt * 16 + l16] = f2b1(oacc[mt][dt][r] * inv);
    }
  }
}

// ---------------------------------------------------------------------------
extern "C" void kernel_launch(void* const* d_in, const int* in_sizes, int n_in,
                              void* d_out, int out_size, void* d_ws, size_t ws_size,
                              hipStream_t stream) {
  const float *x, *Wq, *Wk, *Wv, *Wo;
  if (n_in == 5 && in_sizes[4] == 8388608) {   // alphabetical fallback
    Wk = (const float*)d_in[0]; Wo = (const float*)d_in[1];
    Wq = (const float*)d_in[2]; Wv = (const float*)d_in[3];
    x  = (const float*)d_in[4];
  } else {                                      // dict order (confirmed round 5/6)
    x  = (const float*)d_in[0]; Wq = (const float*)d_in[1];
    Wk = (const float*)d_in[2]; Wv = (const float*)d_in[3];
    Wo = (const float*)d_in[4];
  }
  float* out = (float*)d_out;   // fp32 output (confirmed round 6)

  // Workspace (72 MiB, proven available):
  // [WqT|WkT|WvT] 6MiB | WoT 2MiB | q 16MiB | k 16MiB | vT 16MiB | attn/xb 16MiB
  char* ws = (char*)d_ws;
  ushort_t* wqkvT = (ushort_t*)(ws);
  ushort_t* woT   = (ushort_t*)(ws + 6291456);
  ushort_t* qbuf  = (ushort_t*)(ws + 8388608);
  ushort_t* kbuf  = (ushort_t*)(ws + 8388608 + 16777216);
  ushort_t* vbuf  = (ushort_t*)(ws + 8388608 + 2 * 16777216);
  ushort_t* attn  = (ushort_t*)(ws + 8388608 + 3 * 16777216);
  ushort_t* xb    = attn;   // alias, lifetime-disjoint

  xcast<<<dim3(4096), 256, 0, stream>>>(x, xb);
  transpose_w<<<dim3(16, 16, 4), 256, 0, stream>>>(Wq, Wk, Wv, Wo, wqkvT);
  gemm256<<<dim3(32, 12), 512, 0, stream>>>(xb, wqkvT, qbuf, kbuf, vbuf, nullptr, 1024);
  attn_kernel<<<dim3(NBLK, HH, BB), 256, 0, stream>>>(qbuf, kbuf, vbuf, attn);
  gemmk128<<<dim3(64, 8), 256, 0, stream>>>(attn, woT, out, 1024);
}